// Round 10
// baseline (19.720 us; speedup 1.0000x reference)
//
#include <hip/hip_runtime.h>

#define L 4096
#define NTL 64                // one wave per block, one row per block
#define SS2 36                // scan row stride in words (144B: 16B-aligned, bank-spread)
#define NROWS 130             // 128 halves + 1 pad row each side

typedef unsigned int u32;
typedef unsigned long long u64;

static __device__ __forceinline__ u32 umax(u32 a, u32 b) { return a > b ? a : b; }

// One row per WAVE. Exact greedy NMS via iterative local-max peeling.
// Lane owns 64 elements = two 32-wide halves H0=2*lane, H1=2*lane+1.
// u32 key = bits(|x|)+1 (0 = inactive), keys fully register-resident.
// Half width 32 <= 33 => only a half's FIRST argmax can win; window +-32
// spans exactly halves H-1,H,H+1:
//   blocked-left  iff sfx[H-1][om] >= k   (earlier index wins ties)
//   blocked-right iff pfx[H+1][om] >  k
// Winner exchange via __shfl; termination via __ballot — no flag LDS traffic.
// __syncthreads on a single-wave block is ~free.

#define SCAN_WRITE(OFS, ROWIDX, RUN, OM)                                        \
    do {                                                                        \
        u32 pf_[32], sf_[32];                                                   \
        u32 p_ = 0, nom_ = 0;                                                   \
        _Pragma("unroll")                                                       \
        for (int o_ = 0; o_ < 32; ++o_) {                                       \
            u32 k_ = key[(OFS) + o_];                                           \
            if (k_ > p_) { p_ = k_; nom_ = (u32)o_; }                           \
            pf_[o_] = p_;                                                       \
        }                                                                       \
        u32 s_ = 0;                                                             \
        _Pragma("unroll")                                                       \
        for (int o_ = 31; o_ >= 0; --o_) {                                      \
            s_ = umax(s_, key[(OFS) + o_]); sf_[o_] = s_;                       \
        }                                                                       \
        u32* pr_ = &pfxS[(ROWIDX) * SS2];                                       \
        u32* sr_ = &sfxS[(ROWIDX) * SS2];                                       \
        _Pragma("unroll")                                                       \
        for (int q_ = 0; q_ < 32; q_ += 4) {                                    \
            *reinterpret_cast<uint4*>(pr_ + q_) =                               \
                make_uint4(pf_[q_], pf_[q_ + 1], pf_[q_ + 2], pf_[q_ + 3]);     \
            *reinterpret_cast<uint4*>(sr_ + q_) =                               \
                make_uint4(sf_[q_], sf_[q_ + 1], sf_[q_ + 2], sf_[q_ + 3]);     \
        }                                                                       \
        (RUN) = p_; (OM) = nom_;                                                \
    } while (0)

__global__ __launch_bounds__(NTL) void extrema_nms_kernel(const float* __restrict__ in,
                                                          float* __restrict__ out) {
    __shared__ u32 pfxS[NROWS * SS2];
    __shared__ u32 sfxS[NROWS * SS2];

    const int lane = threadIdx.x;
    const int gbase = lane * 64;
    const float* xrow = in + (size_t)blockIdx.x * L;

    // pad rows 0 and NROWS-1 (only cols < 32 are ever read)
    if (lane < SS2) {
        pfxS[lane] = 0; sfxS[lane] = 0;
        pfxS[(NROWS - 1) * SS2 + lane] = 0;
        sfxS[(NROWS - 1) * SS2 + lane] = 0;
    }

    // ---- streaming key computation -> key[64] in registers ----
    // right[i] = (i<L-1) && x[i+1] >  x[i]; left[i] = (i==0) || x[i] <= x[i-1]
    u32 key[64];
    {
        float xm1 = (lane > 0) ? xrow[gbase - 1] : 0.0f;
        float xp64 = (lane < 63) ? xrow[gbase + 64] : 0.0f;
        float4 cur = *reinterpret_cast<const float4*>(xrow + gbase);
        float prev = xm1;
        #pragma unroll
        for (int g = 0; g < 16; ++g) {
            float4 nxt;
            if (g < 15) nxt = *reinterpret_cast<const float4*>(xrow + gbase + 4 * (g + 1));
            else nxt = make_float4(xp64, 0.f, 0.f, 0.f);
            float e0 = cur.x, e1 = cur.y, e2 = cur.z, e3 = cur.w;
            float pv[4] = {prev, e0, e1, e2};
            float cv[4] = {e0, e1, e2, e3};
            float nv[4] = {e1, e2, e3, nxt.x};
            #pragma unroll
            for (int j = 0; j < 4; ++j) {
                int i = gbase + 4 * g + j;
                float xi = cv[j];
                bool right = (i < L - 1) && (nv[j] > xi);
                bool left = (i == 0) || (xi <= pv[j]);
                bool neg = (xi <= 0.0f);
                bool ext = (right && left && neg) || (!right && !left && !neg);
                key[4 * g + j] = ext ? ((__float_as_uint(xi) & 0x7fffffffu) + 1u) : 0u;
            }
            prev = e3; cur = nxt;
        }
    }

    // ---- initial alive masks + scans -> LDS ----
    u32 aliveL = 0, aliveH = 0;
    #pragma unroll
    for (int o = 0; o < 32; ++o) {
        if (key[o]) aliveL |= (1u << o);
        if (key[32 + o]) aliveH |= (1u << o);
    }
    u32 runL, omL, runH, omH;
    SCAN_WRITE(0, 2 * lane + 1, runL, omL);
    SCAN_WRITE(32, 2 * lane + 2, runH, omH);
    u32 keptL = 0, keptH = 0;
    __syncthreads();

    // ---- peeling rounds (wave-synchronous; 1 cheap barrier/round) ----
    for (int r = 0; r < 200; ++r) {
        // detect: only each half's first argmax can win
        u32 ws = 0;
        if (runL) {
            u32 bL = sfxS[(2 * lane) * SS2 + omL];       // blocks iff >= runL
            u32 bR = pfxS[(2 * lane + 2) * SS2 + omL];   // blocks iff >  runL
            if (bL < runL && bR <= runL) ws = 1u | (omL << 1);
        }
        if (runH) {
            u32 bL = sfxS[(2 * lane + 1) * SS2 + omH];
            u32 bR = pfxS[(2 * lane + 3) * SS2 + omH];
            if (bL < runH && bR <= runH) ws |= (1u << 8) | (omH << 9);
        }
        if (__ballot(ws != 0) == 0) break;               // no candidates left anywhere

        if (ws & 1u)     keptL |= (1u << omL);
        if (ws & 0x100u) keptH |= (1u << omH);

        // winner exchange with lane +-1 (halves H-1 / H+1 live there)
        int lm = (lane == 0) ? 0 : lane - 1;
        int rp = (lane == 63) ? 63 : lane + 1;
        u32 wsL = __shfl(ws, lm); if (lane == 0)  wsL = 0;
        u32 wsR = __shfl(ws, rp); if (lane == 63) wsR = 0;

        // suppression masks (winner at q in H-1 kills [0..q]; in H kills all;
        // in H+1 kills [q..31])
        u32 supLo = 0, supHi = 0;
        if (wsL & 0x100u) { u32 q = (wsL >> 9) & 31u; supLo |= (2u << q) - 1u; }
        if (ws & 0x100u)  { u32 q = (ws >> 9) & 31u;  supLo |= ~((1u << q) - 1u); }
        if (ws & 1u)      supLo = 0xffffffffu;
        if (ws & 1u)      { u32 q = (ws >> 1) & 31u;  supHi |= (2u << q) - 1u; }
        if (wsR & 1u)     { u32 q = (wsR >> 1) & 31u; supHi |= ~((1u << q) - 1u); }
        if (ws & 0x100u)  supHi = 0xffffffffu;

        // rescan halves whose alive set changed
        u32 nA = aliveL & ~supLo;
        if (nA != aliveL) {
            aliveL = nA;
            #pragma unroll
            for (int o = 0; o < 32; ++o) key[o] = ((supLo >> o) & 1u) ? 0u : key[o];
            SCAN_WRITE(0, 2 * lane + 1, runL, omL);
        }
        u32 nB = aliveH & ~supHi;
        if (nB != aliveH) {
            aliveH = nB;
            #pragma unroll
            for (int o = 0; o < 32; ++o) key[32 + o] = ((supHi >> o) & 1u) ? 0u : key[32 + o];
            SCAN_WRITE(32, 2 * lane + 2, runH, omH);
        }
        __syncthreads();   // single-wave: ~free; orders LDS for next detect
    }

    // ---- output: re-read x (L2-hot), mask by kept bits ----
    float* orow = out + (size_t)blockIdx.x * L;
    #pragma unroll
    for (int g = 0; g < 16; ++g) {
        float4 f = *reinterpret_cast<const float4*>(xrow + gbase + 4 * g);
        u32 m = (g < 8) ? keptL : keptH;
        int sh = (4 * g) & 31;
        f.x = ((m >> (sh + 0)) & 1u) ? f.x : 0.0f;
        f.y = ((m >> (sh + 1)) & 1u) ? f.y : 0.0f;
        f.z = ((m >> (sh + 2)) & 1u) ? f.z : 0.0f;
        f.w = ((m >> (sh + 3)) & 1u) ? f.w : 0.0f;
        *reinterpret_cast<float4*>(orow + gbase + 4 * g) = f;
    }
}

extern "C" void kernel_launch(void* const* d_in, const int* in_sizes, int n_in,
                              void* d_out, int out_size, void* d_ws, size_t ws_size,
                              hipStream_t stream) {
    const float* in = (const float*)d_in[0];
    float* out = (float*)d_out;
    int rows = in_sizes[0] / L;   // 128
    extrema_nms_kernel<<<rows, NTL, 0, stream>>>(in, out);
}

// Round 11
// 14.321 us; speedup vs baseline: 1.3770x; 1.3770x over previous
//
#include <hip/hip_runtime.h>

#define L 4096
#define NT 256
#define C 16                  // elements per thread (one chunk per thread)
#define NC (NT + 4)           // chunk rows incl. 2 pads each side
#define SS 20                 // scan row stride in words (80B, 16B-aligned, bank-spread)
#define KSUB 2                // sub-iterations (propagation hops) per barrier

typedef unsigned int u32;
typedef unsigned long long u64;

static __device__ __forceinline__ u32 umax(u32 a, u32 b) { return a > b ? a : b; }

// One block per row. Exact greedy NMS via iterative local-max peeling.
// u32 key = bits(|x|)+1 (0 = inactive). Only a chunk's FIRST argmax can win
// (chunk width 16 <= 33). Ties: left blockers block on >=, right on > —
// exactly stable argsort(-|x|). MONOTONE ASYNC SCHEDULING: keys only get
// zeroed, so stale neighbor scans/winmasks overstate blockers -> can only
// false-BLOCK (delay), never false-win. Hence detect+apply merged, KSUB
// sub-iterations per barrier, and a monotone lastChange stamp for exit.

#define RESCAN()                                                         \
    do {                                                                 \
        u32 pf_[C], sf_[C];                                              \
        u32 p_ = 0, nom_ = 0;                                            \
        _Pragma("unroll")                                                \
        for (int o_ = 0; o_ < C; ++o_) {                                 \
            u32 k_ = key[o_];                                            \
            if (k_ > p_) { p_ = k_; nom_ = (u32)o_; }                    \
            pf_[o_] = p_;                                                \
        }                                                                \
        u32 s_ = 0;                                                      \
        _Pragma("unroll")                                                \
        for (int o_ = C - 1; o_ >= 0; --o_) {                            \
            s_ = umax(s_, key[o_]); sf_[o_] = s_;                        \
        }                                                                \
        u32* pr_ = &pfxS[cc * SS];                                       \
        u32* sr_ = &sfxS[cc * SS];                                       \
        _Pragma("unroll")                                                \
        for (int q_ = 0; q_ < C; q_ += 4) {                              \
            *reinterpret_cast<uint4*>(pr_ + q_) =                        \
                make_uint4(pf_[q_], pf_[q_+1], pf_[q_+2], pf_[q_+3]);    \
            *reinterpret_cast<uint4*>(sr_ + q_) =                        \
                make_uint4(sf_[q_], sf_[q_+1], sf_[q_+2], sf_[q_+3]);    \
        }                                                                \
        TAc[cc] = p_;                                                    \
        run = p_; om = nom_;                                             \
    } while (0)

#define ZERO_SCANS()                                                     \
    do {                                                                 \
        uint4 z_ = make_uint4(0, 0, 0, 0);                               \
        u32* pr_ = &pfxS[cc * SS];                                       \
        u32* sr_ = &sfxS[cc * SS];                                       \
        _Pragma("unroll")                                                \
        for (int q_ = 0; q_ < C; q_ += 4) {                              \
            *reinterpret_cast<uint4*>(pr_ + q_) = z_;                    \
            *reinterpret_cast<uint4*>(sr_ + q_) = z_;                    \
        }                                                                \
        TAc[cc] = 0;                                                     \
    } while (0)

__global__ __launch_bounds__(NT) void extrema_nms_kernel(const float* __restrict__ in,
                                                         float* __restrict__ out) {
    __shared__ u32 pfxS[NC * SS];  // prefix-max per chunk (cols 0..15 used)
    __shared__ u32 sfxS[NC * SS];  // suffix-max per chunk
    __shared__ u32 TAc[NC];        // chunk max, stride-1
    __shared__ u32 winC[NC];       // cumulative winner mask (one-hot or 0)
    __shared__ u32 lastChange;     // monotone round stamp

    const int tid = threadIdx.x;
    const int cc = tid + 2;
    const int base = tid * C;
    const float* xrow = in + (size_t)blockIdx.x * L;

    // ---- pads (written once, never again) ----
    if (tid < 4 * SS) {                      // scan pad rows 0,1,NT+2,NT+3
        int rsel = tid / SS;
        int row = (rsel & 1) + ((rsel >> 1) ? (NT + 2) : 0);
        int col = tid % SS;
        pfxS[row * SS + col] = 0;
        sfxS[row * SS + col] = 0;
    }
    if (tid < 4) {
        int slot = (tid & 1) + ((tid >> 1) ? (NT + 2) : 0);
        TAc[slot] = 0;
        winC[slot] = 0;
    }
    winC[cc] = 0;
    if (tid == 0) lastChange = 0;

    // ---- load own 16 x values + boundary neighbors ----
    float xv[C];
    #pragma unroll
    for (int k = 0; k < C; k += 4) {
        float4 f = *reinterpret_cast<const float4*>(xrow + base + k);
        xv[k] = f.x; xv[k + 1] = f.y; xv[k + 2] = f.z; xv[k + 3] = f.w;
    }
    float xl = (base > 0) ? xrow[base - 1] : 0.0f;
    float xr = (base + C < L) ? xrow[base + C] : 0.0f;

    // ---- extrema mask -> u32 keys ----
    // right[i] = (i<L-1) && x[i+1] >  x[i]; left[i] = (i==0) || x[i] <= x[i-1]
    u32 key[C];
    #pragma unroll
    for (int o = 0; o < C; ++o) {
        int i = base + o;
        float xi = xv[o];
        float xp = (o == 0) ? xl : xv[o - 1];
        float xn = (o == C - 1) ? xr : xv[o + 1];
        bool right = (i < L - 1) && (xn > xi);
        bool left  = (i == 0) || (xi <= xp);
        bool neg   = (xi <= 0.0f);
        bool ext = (right && left && neg) || (!right && !left && !neg);
        key[o] = ext ? ((__float_as_uint(xi) & 0x7fffffffu) + 1u) : 0u;
    }

    // ---- initial alive mask + scans -> LDS ----
    u32 alivem = 0;
    #pragma unroll
    for (int o = 0; o < C; ++o) if (key[o]) alivem |= (1u << o);
    u32 run, om;
    RESCAN();
    u32 keptm = 0;
    u64 appliedW0 = 0;
    u32 appliedW1 = 0;
    __syncthreads();

    // ---- async peeling: KSUB hops per barrier, monotone-stale-safe ----
    for (int r = 1; r <= 200; ++r) {
        bool changedAny = false;
        #pragma unroll
        for (int s = 0; s < KSUB; ++s) {
            if (run) {
                // prefetch: all 8 loads issue together -> one exposed latency
                u32 m0 = winC[cc - 2], m1 = winC[cc - 1];
                u32 m3 = winC[cc + 1], m4 = winC[cc + 2];
                u32 sL = sfxS[(cc - 2) * SS + om];
                u32 tL = TAc[cc - 1];
                u32 tR = TAc[cc + 1];
                u32 pR = pfxS[(cc + 2) * SS + om];

                // ---- apply newly-seen neighbor winners ----
                // W-space [base-32, base+47]: cc-2 bits0-15 | cc-1 16-31 |
                // (own excluded: applied at win) | cc+1 48-63 | cc+2 W1 0-15
                u64 W0 = (u64)m0 | ((u64)m1 << 16) | ((u64)m3 << 48);
                u32 W1 = m4;
                bool omChanged = false;
                if ((W0 ^ appliedW0) | (u64)(W1 ^ appliedW1)) {
                    appliedW0 = W0; appliedW1 = W1;
                    // suppressed(o) iff any winner bit in [o, o+64]
                    u32 supmask = 0;
                    if (W0) { int h0 = 63 - __clzll(W0);
                              supmask = (h0 >= 15) ? 0xffffu : ((2u << h0) - 1u); }
                    if (W1) { int l1 = __ffs((int)W1) - 1;
                              supmask |= ~((1u << l1) - 1u); }
                    u32 nA = alivem & ~supmask;
                    if (nA != alivem) {
                        alivem = nA;
                        changedAny = true;
                        if (nA == 0) {
                            ZERO_SCANS();
                            run = 0;
                        } else {
                            #pragma unroll
                            for (int o = 0; o < C; ++o)
                                key[o] = ((supmask >> o) & 1u) ? 0u : key[o];
                            RESCAN();
                            omChanged = true;
                        }
                    }
                }

                // ---- detect: only the chunk's first argmax can win ----
                if (run) {
                    if (omChanged) {           // om-indexed prefetches invalid
                        sL = sfxS[(cc - 2) * SS + om];
                        pR = pfxS[(cc + 2) * SS + om];
                    }
                    u32 bL = umax(sL, tL);     // blocks iff >= run
                    u32 bR = umax(tR, pR);     // blocks iff >  run
                    if (bL < run && bR <= run) {
                        keptm |= 1u << om;
                        winC[cc] = 1u << om;   // publish (monotone, one-hot)
                        changedAny = true;
                        ZERO_SCANS();          // own chunk fully dies
                        run = 0; alivem = 0;
                    }
                }
            }
        }
        if (changedAny) lastChange = r;        // same-value races benign
        __syncthreads();
        if (lastChange < (u32)r) break;        // quiet round vs current state => fixpoint
    }

    // ---- output straight from registers ----
    float* orow = out + (size_t)blockIdx.x * L;
    #pragma unroll
    for (int k = 0; k < C; k += 4) {
        float4 f;
        f.x = ((keptm >> (k + 0)) & 1u) ? xv[k + 0] : 0.0f;
        f.y = ((keptm >> (k + 1)) & 1u) ? xv[k + 1] : 0.0f;
        f.z = ((keptm >> (k + 2)) & 1u) ? xv[k + 2] : 0.0f;
        f.w = ((keptm >> (k + 3)) & 1u) ? xv[k + 3] : 0.0f;
        *reinterpret_cast<float4*>(orow + base + k) = f;
    }
}

extern "C" void kernel_launch(void* const* d_in, const int* in_sizes, int n_in,
                              void* d_out, int out_size, void* d_ws, size_t ws_size,
                              hipStream_t stream) {
    const float* in = (const float*)d_in[0];
    float* out = (float*)d_out;
    int rows = in_sizes[0] / L;   // 128
    extrema_nms_kernel<<<rows, NT, 0, stream>>>(in, out);
}